// Round 6
// baseline (279.064 us; speedup 1.0000x reference)
//
#include <hip/hip_runtime.h>
#include <stdint.h>

#define BATCH 8
#define NPTS 4096
#define NS 1024
#define KD 6   // sorted-list depth (rows and cols)

typedef unsigned long long u64;
typedef unsigned int u32;
typedef unsigned short u16;
typedef unsigned char u8;

#define DEADV (~0ull)
#define QNANB 0x7FC00000u
#define INFB  0x7F800000u
// key: [51:20]=f32 dist bits, [19:10]=row, [9:0]=col. u64 order == (dist,row,col)
// lexicographic == JAX row-major argmin tie-break. Keys unique per (row,col).
// NaN dist bits sort above all finite distances -> dead coords auto-lose.

__device__ __forceinline__ float pdist3(float ax, float ay, float az,
                                        float bx, float by, float bz) {
    float dx = ax - bx, dy = ay - by, dz = az - bz;
    float d2 = __fmaf_rn(dz, dz, __fmaf_rn(dy, dy, dx * dx));
    return __fsqrt_rn(d2);
}

__device__ __forceinline__ u64 packv(float d, u32 row, u32 col) {
    return ((u64)__float_as_uint(d) << 20) | ((u64)row << 10) | (u64)col;
}

__device__ __forceinline__ u64 u64min2(u64 a, u64 b) { return a < b ? a : b; }

__device__ __forceinline__ u64 tree16(const u64* p) {
    u64 a0 = u64min2(p[0], p[1]),   a1 = u64min2(p[2], p[3]);
    u64 a2 = u64min2(p[4], p[5]),   a3 = u64min2(p[6], p[7]);
    u64 a4 = u64min2(p[8], p[9]),   a5 = u64min2(p[10], p[11]);
    u64 a6 = u64min2(p[12], p[13]), a7 = u64min2(p[14], p[15]);
    u64 b0 = u64min2(a0, a1), b1 = u64min2(a2, a3);
    u64 b2 = u64min2(a4, a5), b3 = u64min2(a6, a7);
    return u64min2(u64min2(b0, b1), u64min2(b2, b3));
}

template<int CTRL>
__device__ __forceinline__ u64 dpp_min_step(u64 m) {
    u32 lo = (u32)m, hi = (u32)(m >> 32);
    u32 olo = (u32)__builtin_amdgcn_update_dpp(-1, (int)lo, CTRL, 0xF, 0xF, false);
    u32 ohi = (u32)__builtin_amdgcn_update_dpp(-1, (int)hi, CTRL, 0xF, 0xF, false);
    u64 o = ((u64)ohi << 32) | olo;
    return o < m ? o : m;
}

// Full-wave u64 min, broadcast to all lanes of this wave.
__device__ __forceinline__ u64 wave_min_u64(u64 m) {
    m = dpp_min_step<0x111>(m); // row_shr:1
    m = dpp_min_step<0x112>(m); // row_shr:2
    m = dpp_min_step<0x114>(m); // row_shr:4
    m = dpp_min_step<0x118>(m); // row_shr:8
    m = dpp_min_step<0x142>(m); // row_bcast15
    m = dpp_min_step<0x143>(m); // row_bcast31
    u32 lo = (u32)__builtin_amdgcn_readlane((int)(u32)m, 63);
    u32 hi = (u32)__builtin_amdgcn_readlane((int)(u32)(m >> 32), 63);
    return ((u64)hi << 32) | lo;
}

template<int CTRL>
__device__ __forceinline__ u64 dpp_or_step(u64 m) {
    u32 lo = (u32)m, hi = (u32)(m >> 32);
    u32 olo = (u32)__builtin_amdgcn_update_dpp(0, (int)lo, CTRL, 0xF, 0xF, false);
    u32 ohi = (u32)__builtin_amdgcn_update_dpp(0, (int)hi, CTRL, 0xF, 0xF, false);
    return m | (((u64)ohi << 32) | olo);
}

// Full-wave u64 OR, broadcast to all lanes of this wave.
__device__ __forceinline__ u64 wave_or_u64(u64 m) {
    m = dpp_or_step<0x111>(m);
    m = dpp_or_step<0x112>(m);
    m = dpp_or_step<0x114>(m);
    m = dpp_or_step<0x118>(m);
    m = dpp_or_step<0x142>(m);
    m = dpp_or_step<0x143>(m);
    u32 lo = (u32)__builtin_amdgcn_readlane((int)(u32)m, 63);
    u32 hi = (u32)__builtin_amdgcn_readlane((int)(u32)(m >> 32), 63);
    return ((u64)hi << 32) | lo;
}

__device__ __forceinline__ float readlane_f(float v, int l) {
    return __uint_as_float((u32)__builtin_amdgcn_readlane((int)__float_as_uint(v), l));
}

__global__ void gather_k(const float* __restrict__ S1, const float* __restrict__ S2,
                         const int* __restrict__ idx,
                         float4* __restrict__ s1g, float4* __restrict__ s2g,
                         int* __restrict__ cnt) {
    int t = blockIdx.x * blockDim.x + threadIdx.x;
    if (t == 0) *cnt = 0;   // reset last-block counter each replay (stream-ordered)
    if (t >= BATCH * NS) return;
    int b = t >> 10;
    int j = idx[t];
    const float* p1 = S1 + ((size_t)b * NPTS + j) * 3;
    const float* p2 = S2 + ((size_t)b * NPTS + j) * 3;
    s1g[t] = make_float4(p1[0], p1[1], p1[2], 0.f);
    s2g[t] = make_float4(p2[0], p2[1], p2[2], 0.f);
}

// One wave per (batch,row) [first half] or (batch,col) [second half]:
// sorted top-KD lists. Scanned (opposite-side) set staged in LDS (block-uniform).
__global__ void lists_k(const float4* __restrict__ s1g, const float4* __restrict__ s2g,
                        u64* __restrict__ rlist_g, u64* __restrict__ clist_g) {
    __shared__ float4 pts[NS];   // 16 KiB
    int gg = blockIdx.x * 4 + (threadIdx.x >> 6);
    int lane = threadIdx.x & 63;
    int side = (gg >= BATCH * NS) ? 1 : 0;   // 0 = rows over cols, 1 = cols over rows
    int g = gg - side * (BATCH * NS);
    int b = g >> 10;            // block-uniform (4 | 1024)
    u32 rc = (u32)(g & 1023);
    const float4* other = (side ? s1g : s2g) + (size_t)b * NS;
    for (int i = threadIdx.x; i < NS; i += 256) pts[i] = other[i];
    float4 a = side ? s2g[g] : s1g[g];
    __syncthreads();
    u64 cand[16];
    #pragma unroll
    for (int k = 0; k < 16; ++k) {
        int o = lane + (k << 6);
        float4 q = pts[o];
        float d = pdist3(a.x, a.y, a.z, q.x, q.y, q.z);
        cand[k] = side ? packv(d, (u32)o, rc) : packv(d, rc, (u32)o);
    }
    u64* out = (side ? clist_g : rlist_g) + (size_t)g * KD;
    for (int i = 0; i < KD; ++i) {
        u64 m1 = wave_min_u64(tree16(cand));
        if (lane == 0) out[i] = m1;
        #pragma unroll
        for (int k = 0; k < 16; ++k) cand[k] = (cand[k] == m1) ? DEADV : cand[k];
    }
}

// One 1024-thread block per batch. Parallel greedy via mutual minima.
// Main loop handles live > 64; when live <= 64, wave 0 finishes the matching
// BARRIER-FREE: one lane per live row AND live col, all state in registers,
// mutual detection via ds_bpermute, kills via ballot + DPP OR-reduce,
// repairs via broadcast-row scan + wave_min. Same u64 keys -> identical
// greedy sequence; each row's single loss lands in the same lred slot ->
// bit-identical final reduction.
__global__ void __launch_bounds__(1024, 1)
resolve_k(const float4* __restrict__ s1g, const float4* __restrict__ s2g,
          const u64* __restrict__ rlist_gl, const u64* __restrict__ clist_gl,
          float* __restrict__ loss_ws, int* __restrict__ cnt,
          float* __restrict__ out) {
    __shared__ u64 rlist[NS * KD];   // 48 KiB
    __shared__ u64 clist[NS * KD];   // 48 KiB
    __shared__ u64 rmin[NS];         // 8 KiB
    __shared__ u64 cmin[NS];         // 8 KiB
    __shared__ float4 s1c[NS];       // 16 KiB compact coords (.w = orig idx bits)
    __shared__ float4 s2c[NS];       // 16 KiB
    __shared__ float4 e1c[64], e2c[64];              // 2 KiB endgame coords
    __shared__ u16 pos1[NS], pos2[NS];               // 4 KiB (orig -> compact pos)
    __shared__ u32 am1[NS / 32], am2[NS / 32];       // 256 B liveness bitmasks
    __shared__ u8 rptrs[NS], cptrs[NS];              // 2 KiB
    __shared__ u16 qrow[NS], qcol[NS];               // 4 KiB
    __shared__ int wcntr[16], wcntc[16];             // 128 B
    __shared__ int qrn, qcn, matched, stale_n;
    float* lred = (float*)rlist;     // aliased: rlist dead after the round loop
    int b = blockIdx.x;
    int tid = threadIdx.x;
    int lane = tid & 63, wv = tid >> 6;

    {   // coalesced list copies (1536 float4 each)
        const float4* rs = (const float4*)(rlist_gl + (size_t)b * NS * KD);
        const float4* cs = (const float4*)(clist_gl + (size_t)b * NS * KD);
        float4* rd = (float4*)rlist;
        float4* cd = (float4*)clist;
        for (int i = tid; i < NS * KD / 2; i += 1024) { rd[i] = rs[i]; cd[i] = cs[i]; }
    }
    {
        float4 v1 = s1g[(size_t)b * NS + tid]; v1.w = __uint_as_float((u32)tid);
        s1c[tid] = v1;
        float4 v2 = s2g[(size_t)b * NS + tid]; v2.w = __uint_as_float((u32)tid);
        s2c[tid] = v2;
    }
    pos1[tid] = (u16)tid; pos2[tid] = (u16)tid;
    rptrs[tid] = 1; cptrs[tid] = 1;
    if (tid < NS / 32) { am1[tid] = ~0u; am2[tid] = ~0u; }
    if (tid == 0) { matched = 0; stale_n = NS; }
    __syncthreads();
    rmin[tid] = rlist[tid * KD];
    cmin[tid] = clist[tid * KD];
    float loss = 0.f;
    __syncthreads();

#define ALIVE1(i) ((am1[(u32)(i) >> 5] >> ((u32)(i) & 31u)) & 1u)
#define ALIVE2(i) ((am2[(u32)(i) >> 5] >> ((u32)(i) & 31u)) & 1u)

    int elive = 0;   // set when switching to the single-wave endgame
    for (int round = 0; round < NS; ++round) {
        // ---- A: mutual detection ----
        u64 myk = rmin[tid];
        u32 c = (u32)myk & 1023u;
        bool mut = (myk != DEADV) && (cmin[c] == myk);
        __syncthreads();
        // ---- B: apply kills (bitmask + NaN the compact entry) ----
        if (mut) {
            loss += __uint_as_float((u32)(myk >> 20));
            rmin[tid] = DEADV;
            cmin[c] = DEADV;
            atomicAnd(&am1[tid >> 5], ~(1u << (tid & 31)));
            atomicAnd(&am2[c >> 5],   ~(1u << (c & 31)));
            s1c[pos1[tid]].x = __uint_as_float(QNANB);
            s2c[pos2[c]].x   = __uint_as_float(QNANB);
        }
        u64 bal = __ballot((int)mut);
        if (lane == 0 && bal) atomicAdd(&matched, (int)__popcll(bal));
        if (tid == 0) { qrn = 0; qcn = 0; }
        __syncthreads();
        int m = matched;
        if (m >= NS) break;
        int live = NS - m;
        if (live <= 64) { elive = live; break; }   // uniform: hand off to endgame
        int stale = stale_n;
        bool rebuild = (stale * 4 > live * 5 + 64);   // block-uniform
        // ---- C: per-thread pop repair (liveness = bitmask) ----
        u64 rk = rmin[tid];
        if (rk != DEADV) {
            if (!ALIVE2((u32)rk & 1023u)) {
                u32 p = rptrs[tid];
                bool found = false;
                while (p < KD) {
                    u64 e = rlist[tid * KD + p];
                    ++p;
                    if (e != DEADV && ALIVE2((u32)e & 1023u)) {
                        rmin[tid] = e; found = true; break;
                    }
                }
                rptrs[tid] = (u8)p;
                if (!found) { int s = atomicAdd(&qrn, 1); qrow[s] = (u16)tid; }
            }
        }
        u64 ck = cmin[tid];
        if (ck != DEADV) {
            if (!ALIVE1(((u32)ck >> 10) & 1023u)) {
                u32 p = cptrs[tid];
                bool found = false;
                while (p < KD) {
                    u64 e = clist[tid * KD + p];
                    ++p;
                    if (e != DEADV && ALIVE1(((u32)e >> 10) & 1023u)) {
                        cmin[tid] = e; found = true; break;
                    }
                }
                cptrs[tid] = (u8)p;
                if (!found) { int s = atomicAdd(&qcn, 1); qcol[s] = (u16)tid; }
            }
        }
        // ---- C2: LAZY ORDERED compaction of coordinate arrays (rare).
        if (rebuild) {
            bool calive = ALIVE2(tid) != 0u;
            bool ralive = ALIVE1(tid) != 0u;
            float4 cv, rv;
            if (calive) cv = s2c[pos2[tid]];
            if (ralive) rv = s1c[pos1[tid]];
            u64 cb = __ballot((int)calive);
            u64 rb = __ballot((int)ralive);
            if (lane == 0) { wcntc[wv] = (int)__popcll(cb); wcntr[wv] = (int)__popcll(rb); }
            __syncthreads();
            int cbase = 0, rbase = 0;
            for (int j = 0; j < wv; ++j) { cbase += wcntc[j]; rbase += wcntr[j]; }
            int crank = (int)__popcll(cb & ((1ull << lane) - 1ull));
            int rrank = (int)__popcll(rb & ((1ull << lane) - 1ull));
            if (calive) { int np = cbase + crank; pos2[tid] = (u16)np; s2c[np] = cv; }
            if (ralive) { int np = rbase + rrank; pos1[tid] = (u16)np; s1c[np] = rv; }
        }
        __syncthreads();
        int nr = qrn, nc = qcn;
        int scan_n = rebuild ? live : stale;   // live rows == live cols == NS - matched
        if (rebuild && tid == 0) stale_n = live;  // consumed next round (post-barrier)
        // ---- D: merged rescan queue; LINEAR scan of compact coords ----
        int tot = nr + nc;
        for (int qi = wv; qi < tot; qi += 16) {
            if (qi < nr) {
                u32 r = qrow[qi];
                float4 a = s1c[pos1[r]];
                float a1d = __uint_as_float(INFB), a2d = a1d;
                u32 a1i = 1023u, a2i = 1023u;
                #pragma unroll 4
                for (int i = lane; i < scan_n; i += 64) {
                    float4 q = s2c[i];                       // affine b128, no indirection
                    float d = pdist3(a.x, a.y, a.z, q.x, q.y, q.z);
                    u32 ci = __float_as_uint(q.w);
                    bool c1 = d < a1d;                       // NaN (dead) never inserted
                    bool c2 = d < a2d;
                    float td = c2 ? d : a2d;  u32 ti = c2 ? ci : a2i;
                    a2d = c1 ? a1d : td;      a2i = c1 ? a1i : ti;
                    a1d = c1 ? d : a1d;       a1i = c1 ? ci : a1i;
                }
                u32 b1 = __float_as_uint(a1d), b2 = __float_as_uint(a2d);
                u64 m1 = (b1 == INFB) ? DEADV : (((u64)b1 << 10) | a1i);
                u64 m2 = (b2 == INFB) ? DEADV : (((u64)b2 << 10) | a2i);
                u64 M1 = wave_min_u64(m1);
                u64 ck2 = (m1 == M1) ? m2 : m1;   // unique keys: one lane holds M1
                u64 M2 = wave_min_u64(ck2);
                if (lane == 0) {
                    u64 F1 = ((M1 >> 10) << 20) | ((u64)r << 10) | (M1 & 1023u);
                    u64 F2 = (M2 == DEADV) ? DEADV
                           : (((M2 >> 10) << 20) | ((u64)r << 10) | (M2 & 1023u));
                    rmin[r] = F1;
                    rlist[r * KD + KD - 1] = F2;   // refill tail (checked on pop)
                    rptrs[r] = KD - 1;
                }
            } else {
                u32 cc = qcol[qi - nr];
                float4 a = s2c[pos2[cc]];
                float a1d = __uint_as_float(INFB), a2d = a1d;
                u32 a1i = 1023u, a2i = 1023u;
                #pragma unroll 4
                for (int i = lane; i < scan_n; i += 64) {
                    float4 q = s1c[i];
                    float d = pdist3(q.x, q.y, q.z, a.x, a.y, a.z);
                    u32 ri = __float_as_uint(q.w);
                    bool c1 = d < a1d;
                    bool c2 = d < a2d;
                    float td = c2 ? d : a2d;  u32 ti = c2 ? ri : a2i;
                    a2d = c1 ? a1d : td;      a2i = c1 ? a1i : ti;
                    a1d = c1 ? d : a1d;       a1i = c1 ? ri : a1i;
                }
                u32 b1 = __float_as_uint(a1d), b2 = __float_as_uint(a2d);
                u64 m1 = (b1 == INFB) ? DEADV : (((u64)b1 << 10) | a1i);
                u64 m2 = (b2 == INFB) ? DEADV : (((u64)b2 << 10) | a2i);
                u64 M1 = wave_min_u64(m1);
                u64 ck2 = (m1 == M1) ? m2 : m1;
                u64 M2 = wave_min_u64(ck2);
                if (lane == 0) {
                    u64 F1 = ((M1 >> 10) << 20) | ((M1 & 1023u) << 10) | (u64)cc;
                    u64 F2 = (M2 == DEADV) ? DEADV
                           : (((M2 >> 10) << 20) | ((M2 & 1023u) << 10) | (u64)cc);
                    cmin[cc] = F1;
                    clist[cc * KD + KD - 1] = F2;
                    cptrs[cc] = KD - 1;
                }
            }
        }
        __syncthreads();
    }

    // ---- endgame handoff: ordered compaction of live rows/cols + coords ----
    if (elive > 0) {
        bool ralive = ALIVE1(tid) != 0u;
        bool calive = ALIVE2(tid) != 0u;
        u64 rb = __ballot((int)ralive);
        u64 cb = __ballot((int)calive);
        if (lane == 0) { wcntr[wv] = (int)__popcll(rb); wcntc[wv] = (int)__popcll(cb); }
        __syncthreads();
        int rbase = 0, cbase = 0;
        for (int j = 0; j < wv; ++j) { rbase += wcntr[j]; cbase += wcntc[j]; }
        int rrank = (int)__popcll(rb & ((1ull << lane) - 1ull));
        int crank = (int)__popcll(cb & ((1ull << lane) - 1ull));
        if (ralive) { int np = rbase + rrank; qrow[np] = (u16)tid; e1c[np] = s1c[pos1[tid]]; }
        if (calive) { int np = cbase + crank; qcol[np] = (u16)tid; e2c[np] = s2c[pos2[tid]]; }
    }
    __syncthreads();
    lred[tid] = loss;      // lred aliases rlist (dead now); endgame never touches rlist
    __syncthreads();

    // ---- single-wave barrier-free endgame (wave 0 only) ----
    if (elive > 0 && wv == 0) {
        int j = lane;
        bool aliveR = j < elive, aliveC = j < elive;
        float4 rp = e1c[j];
        float4 cp = e2c[j];
        u32 rorig = (u32)qrow[j], corig = (u32)qcol[j];
        // init: recompute rmin/cmin over the live set (== heap-head invariant)
        u64 rmk = DEADV, cmk = DEADV;
        u32 rmp = 0, cmp_ = 0;
        for (int k = 0; k < elive; ++k) {
            float4 ckp = e2c[k]; u32 cko = (u32)qcol[k];     // broadcast reads
            float dr = pdist3(rp.x, rp.y, rp.z, ckp.x, ckp.y, ckp.z);
            u64 kr = ((u64)__float_as_uint(dr) << 20) | ((u64)rorig << 10) | cko;
            if (aliveR && kr < rmk) { rmk = kr; rmp = (u32)k; }
            float4 rkp = e1c[k]; u32 rko = (u32)qrow[k];
            float dc = pdist3(rkp.x, rkp.y, rkp.z, cp.x, cp.y, cp.z);
            u64 kc = ((u64)__float_as_uint(dc) << 20) | ((u64)rko << 10) | corig;
            if (aliveC && kc < cmk) { cmk = kc; cmp_ = (u32)k; }
        }
        float eloss = 0.f;
        bool ematched = false;
        while (__ballot((int)aliveR) != 0ull) {
            // mutual detection: cmin at the compact col slot of my min
            int addr = (int)(rmp << 2);
            u32 pl = (u32)__builtin_amdgcn_ds_bpermute(addr, (int)(u32)cmk);
            u32 ph = (u32)__builtin_amdgcn_ds_bpermute(addr, (int)(u32)(cmk >> 32));
            u64 cmin_at = ((u64)ph << 32) | pl;
            bool mut = aliveR && (cmin_at == rmk);
            u64 mutmask = __ballot((int)mut);                 // rows killed (by slot)
            u64 ckill = wave_or_u64(mut ? (1ull << rmp) : 0ull); // cols killed (by slot)
            if (mut) { eloss = __uint_as_float((u32)(rmk >> 20)); ematched = true; aliveR = false; }
            if ((ckill >> j) & 1ull) aliveC = false;
            // repairs: serial over wave-uniform masks, one wave_min each
            bool rrep = aliveR && ((ckill >> rmp) & 1ull);
            bool crep = aliveC && ((mutmask >> cmp_) & 1ull);
            u64 rrm = __ballot((int)rrep);
            while (rrm) {
                int jr = (int)(__ffsll((long long)rrm) - 1); rrm &= rrm - 1ull;
                float rx = readlane_f(rp.x, jr), ry = readlane_f(rp.y, jr), rz = readlane_f(rp.z, jr);
                u32 ro = (u32)__builtin_amdgcn_readlane((int)rorig, jr);
                u64 kk = DEADV;
                if (aliveC) {
                    float d = pdist3(rx, ry, rz, cp.x, cp.y, cp.z);
                    kk = ((u64)__float_as_uint(d) << 20) | ((u64)ro << 10) | corig;
                }
                u64 M = wave_min_u64(kk);
                u64 eq = __ballot((int)(kk == M));
                u32 np = (u32)(__ffsll((long long)eq) - 1);
                if (j == jr) { rmk = M; rmp = np; }
            }
            u64 crm = __ballot((int)crep);
            while (crm) {
                int jc = (int)(__ffsll((long long)crm) - 1); crm &= crm - 1ull;
                float cx = readlane_f(cp.x, jc), cy = readlane_f(cp.y, jc), cz = readlane_f(cp.z, jc);
                u32 co = (u32)__builtin_amdgcn_readlane((int)corig, jc);
                u64 kk = DEADV;
                if (aliveR) {
                    float d = pdist3(rp.x, rp.y, rp.z, cx, cy, cz);
                    kk = ((u64)__float_as_uint(d) << 20) | ((u64)rorig << 10) | co;
                }
                u64 M = wave_min_u64(kk);
                u64 eq = __ballot((int)(kk == M));
                u32 np = (u32)(__ffsll((long long)eq) - 1);
                if (j == jc) { cmk = M; cmp_ = np; }
            }
        }
        // deposit each row's single loss into ITS OWN slot (bit-exact tree input)
        if (ematched) lred[rorig] += eloss;   // disjoint rorig, main loss there == 0
    }
    __syncthreads();

    // deterministic block reduction of per-thread losses (order preserved bit-exactly)
    #pragma unroll
    for (int s = 512; s > 0; s >>= 1) {
        if (tid < s) lred[tid] += lred[tid + s];
        __syncthreads();
    }
    if (tid == 0) {
        atomicExch(&loss_ws[b], lred[0] * (1.0f / NS));  // device-scope publish
        __threadfence();
        int old = atomicAdd(cnt, 1);
        if (old == BATCH - 1) {            // last block: deterministic fixed-order sum
            __threadfence();
            float s = 0.f;
            for (int i = 0; i < BATCH; ++i) s += atomicAdd(&loss_ws[i], 0.0f);
            out[0] = s * (1.0f / BATCH);
        }
    }
}

extern "C" void kernel_launch(void* const* d_in, const int* in_sizes, int n_in,
                              void* d_out, int out_size, void* d_ws, size_t ws_size,
                              hipStream_t stream) {
    const float* S1 = (const float*)d_in[0];
    const float* S2 = (const float*)d_in[1];
    const int* idx  = (const int*)d_in[2];
    char* ws = (char*)d_ws;
    size_t o = 0;
    float4* s1g    = (float4*)(ws + o); o += (size_t)BATCH * NS * 16;
    float4* s2g    = (float4*)(ws + o); o += (size_t)BATCH * NS * 16;
    u64* rlist_g   = (u64*)(ws + o);    o += (size_t)BATCH * NS * KD * 8;
    u64* clist_g   = (u64*)(ws + o);    o += (size_t)BATCH * NS * KD * 8;
    float* loss_ws = (float*)(ws + o);  o += (size_t)BATCH * 4;
    int* cnt       = (int*)(ws + o);

    gather_k<<<(BATCH * NS + 255) / 256, 256, 0, stream>>>(S1, S2, idx, s1g, s2g, cnt);
    lists_k<<<2 * BATCH * NS / 4, 256, 0, stream>>>(s1g, s2g, rlist_g, clist_g);
    resolve_k<<<BATCH, 1024, 0, stream>>>(s1g, s2g, rlist_g, clist_g, loss_ws, cnt,
                                          (float*)d_out);
}

// Round 7
// 196.512 us; speedup vs baseline: 1.4201x; 1.4201x over previous
//
#include <hip/hip_runtime.h>
#include <stdint.h>

#define BATCH 8
#define NPTS 4096
#define NS 1024
#define KD 6   // sorted-list depth (rows and cols)

typedef unsigned long long u64;
typedef unsigned int u32;
typedef unsigned short u16;
typedef unsigned char u8;

#define DEADV (~0ull)
#define QNANB 0x7FC00000u
// key: [51:20]=f32 dist bits, [19:10]=row, [9:0]=col. u64 order == (dist,row,col)
// lexicographic == JAX row-major argmin tie-break. Keys unique per (row,col).
// NaN dist bits sort above all finite distances -> dead coords auto-lose.

__device__ __forceinline__ float pdist3(float ax, float ay, float az,
                                        float bx, float by, float bz) {
    float dx = ax - bx, dy = ay - by, dz = az - bz;
    float d2 = __fmaf_rn(dz, dz, __fmaf_rn(dy, dy, dx * dx));
    return __fsqrt_rn(d2);
}

__device__ __forceinline__ u64 packv(float d, u32 row, u32 col) {
    return ((u64)__float_as_uint(d) << 20) | ((u64)row << 10) | (u64)col;
}

__device__ __forceinline__ u64 u64min2(u64 a, u64 b) { return a < b ? a : b; }
__device__ __forceinline__ u64 u64max2(u64 a, u64 b) { return a > b ? a : b; }

__device__ __forceinline__ u64 tree16(const u64* p) {
    u64 a0 = u64min2(p[0], p[1]),   a1 = u64min2(p[2], p[3]);
    u64 a2 = u64min2(p[4], p[5]),   a3 = u64min2(p[6], p[7]);
    u64 a4 = u64min2(p[8], p[9]),   a5 = u64min2(p[10], p[11]);
    u64 a6 = u64min2(p[12], p[13]), a7 = u64min2(p[14], p[15]);
    u64 b0 = u64min2(a0, a1), b1 = u64min2(a2, a3);
    u64 b2 = u64min2(a4, a5), b3 = u64min2(a6, a7);
    return u64min2(u64min2(b0, b1), u64min2(b2, b3));
}

template<int CTRL>
__device__ __forceinline__ u64 dpp_min_step(u64 m) {
    u32 lo = (u32)m, hi = (u32)(m >> 32);
    u32 olo = (u32)__builtin_amdgcn_update_dpp(-1, (int)lo, CTRL, 0xF, 0xF, false);
    u32 ohi = (u32)__builtin_amdgcn_update_dpp(-1, (int)hi, CTRL, 0xF, 0xF, false);
    u64 o = ((u64)ohi << 32) | olo;
    return o < m ? o : m;
}

// Full-wave u64 min, broadcast to all lanes of this wave.
__device__ __forceinline__ u64 wave_min_u64(u64 m) {
    m = dpp_min_step<0x111>(m); // row_shr:1
    m = dpp_min_step<0x112>(m); // row_shr:2
    m = dpp_min_step<0x114>(m); // row_shr:4
    m = dpp_min_step<0x118>(m); // row_shr:8
    m = dpp_min_step<0x142>(m); // row_bcast15
    m = dpp_min_step<0x143>(m); // row_bcast31
    u32 lo = (u32)__builtin_amdgcn_readlane((int)(u32)m, 63);
    u32 hi = (u32)__builtin_amdgcn_readlane((int)(u32)(m >> 32), 63);
    return ((u64)hi << 32) | lo;
}

__global__ void gather_k(const float* __restrict__ S1, const float* __restrict__ S2,
                         const int* __restrict__ idx,
                         float4* __restrict__ s1g, float4* __restrict__ s2g,
                         int* __restrict__ cnt, u64* __restrict__ calib) {
    int t = blockIdx.x * blockDim.x + threadIdx.x;
    if (t == 0) *cnt = 0;   // reset last-block counter each replay (stream-ordered)
    // WRITE_SIZE calibration: exactly 4096 nt stores to distinct 64B lines.
    if (calib && blockIdx.x == 0 && threadIdx.x < 64) {
        for (int k = 0; k < 64; ++k) {
            __builtin_nontemporal_store(0ull,
                calib + ((size_t)threadIdx.x * 64 + k) * 8);
        }
    }
    if (t >= BATCH * NS) return;
    int b = t >> 10;
    int j = idx[t];
    const float* p1 = S1 + ((size_t)b * NPTS + j) * 3;
    const float* p2 = S2 + ((size_t)b * NPTS + j) * 3;
    s1g[t] = make_float4(p1[0], p1[1], p1[2], 0.f);
    s2g[t] = make_float4(p2[0], p2[1], p2[2], 0.f);
}

// One wave per (batch,row) [first half] or (batch,col) [second half]:
// sorted top-KD lists. Scanned (opposite-side) set staged in LDS (block-uniform).
__global__ void lists_k(const float4* __restrict__ s1g, const float4* __restrict__ s2g,
                        u64* __restrict__ rlist_g, u64* __restrict__ clist_g) {
    __shared__ float4 pts[NS];   // 16 KiB
    int gg = blockIdx.x * 4 + (threadIdx.x >> 6);
    int lane = threadIdx.x & 63;
    int side = (gg >= BATCH * NS) ? 1 : 0;   // 0 = rows over cols, 1 = cols over rows
    int g = gg - side * (BATCH * NS);
    int b = g >> 10;            // block-uniform (4 | 1024)
    u32 rc = (u32)(g & 1023);
    const float4* other = (side ? s1g : s2g) + (size_t)b * NS;
    for (int i = threadIdx.x; i < NS; i += 256) pts[i] = other[i];
    float4 a = side ? s2g[g] : s1g[g];
    __syncthreads();
    u64 cand[16];
    #pragma unroll
    for (int k = 0; k < 16; ++k) {
        int o = lane + (k << 6);
        float4 q = pts[o];
        float d = pdist3(a.x, a.y, a.z, q.x, q.y, q.z);
        cand[k] = side ? packv(d, (u32)o, rc) : packv(d, rc, (u32)o);
    }
    u64* out = (side ? clist_g : rlist_g) + (size_t)g * KD;
    for (int i = 0; i < KD; ++i) {
        u64 m1 = wave_min_u64(tree16(cand));
        if (lane == 0) out[i] = m1;
        #pragma unroll
        for (int k = 0; k < 16; ++k) cand[k] = (cand[k] == m1) ? DEADV : cand[k];
    }
}

// One 1024-thread block per batch. Parallel greedy via mutual minima.
// Rebased on the best-measured variant (round-1, resolve 160 us): float4
// coords + NaN liveness + lazy unordered compaction + u64 running top-2.
// NEW: (1) A/B fused -- the barrier between mutual-detect and kill is
// removable: kills only flip cmin[c] K->DEADV, and any concurrent reader's
// (cmin[c]==myk) test is false under either value (keys unique; the only
// thread whose key matches col c IS the killer). rmin writes are self-only;
// coord NaNs are first read in C, after the kept barrier. (2) one nt store
// per round encodes round count in WRITE_SIZE (instrumentation).
__global__ void __launch_bounds__(1024, 1)
resolve_k(const float4* __restrict__ s1g, const float4* __restrict__ s2g,
          const u64* __restrict__ rlist_gl, const u64* __restrict__ clist_gl,
          float* __restrict__ loss_ws, int* __restrict__ cnt,
          float* __restrict__ out, u64* __restrict__ instr) {
    __shared__ u64 rlist[NS * KD];   // 48 KiB
    __shared__ u64 clist[NS * KD];   // 48 KiB
    __shared__ u64 rmin[NS];         // 8 KiB
    __shared__ u64 cmin[NS];         // 8 KiB
    __shared__ float4 s1p[NS];       // 16 KiB (.x==NaN marks dead)
    __shared__ float4 s2p[NS];       // 16 KiB
    __shared__ u8 rptrs[NS], cptrs[NS];              // 2 KiB
    __shared__ u16 qrow[NS], qcol[NS];               // 4 KiB
    __shared__ u16 lrows[NS], lcols[NS];             // 4 KiB (stale-superset live sets)
    __shared__ float lred[1024];                     // 4 KiB
    __shared__ int qrn, qcn, matched, nlr, nlc, stale_n;
    int b = blockIdx.x;
    int tid = threadIdx.x;
    int lane = tid & 63, wv = tid >> 6;

    {   // coalesced list copies (1536 float4 each)
        const float4* rs = (const float4*)(rlist_gl + (size_t)b * NS * KD);
        const float4* cs = (const float4*)(clist_gl + (size_t)b * NS * KD);
        float4* rd = (float4*)rlist;
        float4* cd = (float4*)clist;
        for (int i = tid; i < NS * KD / 2; i += 1024) { rd[i] = rs[i]; cd[i] = cs[i]; }
    }
    s1p[tid] = s1g[(size_t)b * NS + tid];
    s2p[tid] = s2g[(size_t)b * NS + tid];
    rptrs[tid] = 1; cptrs[tid] = 1;
    lrows[tid] = (u16)tid; lcols[tid] = (u16)tid;
    if (tid == 0) { matched = 0; stale_n = NS; }
    __syncthreads();
    rmin[tid] = rlist[tid * KD];
    cmin[tid] = clist[tid * KD];
    float loss = 0.f;
    __syncthreads();

    for (int round = 0; round < NS; ++round) {
        // ---- A+B fused: mutual detection + kills (no barrier between) ----
        u64 myk = rmin[tid];
        u32 c = (u32)myk & 1023u;
        bool mut = (myk != DEADV) && (cmin[c] == myk);
        if (mut) {
            loss += __uint_as_float((u32)(myk >> 20));
            rmin[tid] = DEADV;
            cmin[c] = DEADV;
            s1p[tid].x = __uint_as_float(QNANB);
            s2p[c].x   = __uint_as_float(QNANB);
        }
        u64 bal = __ballot((int)mut);
        if (lane == 0 && bal) atomicAdd(&matched, (int)__popcll(bal));
        if (tid == 0) { qrn = 0; qcn = 0; nlr = 0; nlc = 0; }
        // round-count instrumentation: 1 nt u64 store per (block, round)
        if (instr && tid == 1 && round < 256)
            __builtin_nontemporal_store(0ull, instr + ((size_t)b * 256 + round) * 8);
        __syncthreads();
        int m = matched;
        if (m >= NS) break;
        int live = NS - m;
        int stale = stale_n;
        bool rebuild = (stale * 4 > live * 5 + 64);   // block-uniform
        // ---- C: per-thread pop repair (liveness = .x not NaN) ----
        u64 rk = rmin[tid];
        if (rk != DEADV) {
            float pr = s2p[(u32)rk & 1023u].x;
            if (pr != pr) {
                u32 p = rptrs[tid];
                bool found = false;
                while (p < KD) {
                    u64 e = rlist[tid * KD + p];
                    ++p;
                    if (e != DEADV) {
                        float q = s2p[(u32)e & 1023u].x;
                        if (q == q) { rmin[tid] = e; found = true; break; }
                    }
                }
                rptrs[tid] = (u8)p;
                if (!found) { int s = atomicAdd(&qrn, 1); qrow[s] = (u16)tid; }
            }
        }
        u64 ck = cmin[tid];
        if (ck != DEADV) {
            float pr = s1p[((u32)ck >> 10) & 1023u].x;
            if (pr != pr) {
                u32 p = cptrs[tid];
                bool found = false;
                while (p < KD) {
                    u64 e = clist[tid * KD + p];
                    ++p;
                    if (e != DEADV) {
                        float q = s1p[((u32)e >> 10) & 1023u].x;
                        if (q == q) { cmin[tid] = e; found = true; break; }
                    }
                }
                cptrs[tid] = (u8)p;
                if (!found) { int s = atomicAdd(&qcn, 1); qcol[s] = (u16)tid; }
            }
        }
        // ---- C2: LAZY compaction (only when stale list >1.25x live).
        // Membership deterministic; order not -- min-reduction on u64 keys is
        // order-independent -> exact results.
        if (rebuild) {
            float cx = s2p[tid].x;
            bool calive = (cx == cx);
            u64 cb = __ballot((int)calive);
            int crank = (int)__popcll(cb & ((1ull << lane) - 1ull));
            int cbase = 0;
            if (lane == 0) cbase = atomicAdd(&nlc, (int)__popcll(cb));
            cbase = __shfl(cbase, 0, 64);
            if (calive) lcols[cbase + crank] = (u16)tid;

            float rx = s1p[tid].x;
            bool ralive = (rx == rx);
            u64 rb = __ballot((int)ralive);
            int rrank = (int)__popcll(rb & ((1ull << lane) - 1ull));
            int rbase = 0;
            if (lane == 0) rbase = atomicAdd(&nlr, (int)__popcll(rb));
            rbase = __shfl(rbase, 0, 64);
            if (ralive) lrows[rbase + rrank] = (u16)tid;
        }
        __syncthreads();
        int nr = qrn, nc = qcn;
        int scan_n = rebuild ? live : stale;   // live rows == live cols == NS - matched
        if (rebuild && tid == 0) stale_n = live;  // consumed next round (post-barrier)
        // ---- D: exhaustion rescans over (stale) compact sets, running top-2 ----
        for (int qi = wv; qi < nr; qi += 16) {
            u32 r = qrow[qi];
            float4 a = s1p[r];
            u64 m1 = DEADV, m2 = DEADV;
            for (int i = lane; i < scan_n; i += 64) {
                int cc = lcols[i];
                float4 q = s2p[cc];                      // one ds_read_b128
                float d = pdist3(a.x, a.y, a.z, q.x, q.y, q.z);
                u64 p = packv(d, r, (u32)cc);            // dead -> NaN key, auto-loses
                u64 mx = u64max2(p, m1);
                m1 = u64min2(m1, p);
                m2 = u64min2(m2, mx);
            }
            u64 M1 = wave_min_u64(m1);
            u64 c2 = (m1 == M1) ? m2 : m1;     // unique keys: one lane holds M1
            u64 M2 = wave_min_u64(c2);
            if (lane == 0) {
                rmin[r] = M1;
                rlist[r * KD + KD - 1] = M2;   // refill tail (liveness-checked on pop)
                rptrs[r] = KD - 1;
            }
        }
        for (int qi = wv; qi < nc; qi += 16) {
            u32 cc = qcol[qi];
            float4 a = s2p[cc];
            u64 m1 = DEADV, m2 = DEADV;
            for (int i = lane; i < scan_n; i += 64) {
                int r = lrows[i];
                float4 q = s1p[r];
                float d = pdist3(q.x, q.y, q.z, a.x, a.y, a.z);
                u64 p = packv(d, (u32)r, cc);
                u64 mx = u64max2(p, m1);
                m1 = u64min2(m1, p);
                m2 = u64min2(m2, mx);
            }
            u64 M1 = wave_min_u64(m1);
            u64 c2 = (m1 == M1) ? m2 : m1;
            u64 M2 = wave_min_u64(c2);
            if (lane == 0) {
                cmin[cc] = M1;
                clist[cc * KD + KD - 1] = M2;
                cptrs[cc] = KD - 1;
            }
        }
        __syncthreads();
    }

    // deterministic block reduction of per-thread losses (order preserved bit-exactly)
    lred[tid] = loss;
    __syncthreads();
    #pragma unroll
    for (int s = 512; s > 0; s >>= 1) {
        if (tid < s) lred[tid] += lred[tid + s];
        __syncthreads();
    }
    if (tid == 0) {
        atomicExch(&loss_ws[b], lred[0] * (1.0f / NS));  // device-scope publish
        __threadfence();
        int old = atomicAdd(cnt, 1);
        if (old == BATCH - 1) {            // last block: deterministic fixed-order sum
            __threadfence();
            float s = 0.f;
            for (int i = 0; i < BATCH; ++i) s += atomicAdd(&loss_ws[i], 0.0f);
            out[0] = s * (1.0f / BATCH);
        }
    }
}

extern "C" void kernel_launch(void* const* d_in, const int* in_sizes, int n_in,
                              void* d_out, int out_size, void* d_ws, size_t ws_size,
                              hipStream_t stream) {
    const float* S1 = (const float*)d_in[0];
    const float* S2 = (const float*)d_in[1];
    const int* idx  = (const int*)d_in[2];
    char* ws = (char*)d_ws;
    size_t o = 0;
    float4* s1g    = (float4*)(ws + o); o += (size_t)BATCH * NS * 16;
    float4* s2g    = (float4*)(ws + o); o += (size_t)BATCH * NS * 16;
    u64* rlist_g   = (u64*)(ws + o);    o += (size_t)BATCH * NS * KD * 8;
    u64* clist_g   = (u64*)(ws + o);    o += (size_t)BATCH * NS * KD * 8;
    float* loss_ws = (float*)(ws + o);  o += (size_t)BATCH * 4;
    int* cnt       = (int*)(ws + o);    o += 64;
    o = (o + 4095) & ~(size_t)4095;     // align
    u64* calib     = (u64*)(ws + o);    o += (size_t)4096 * 64;      // 256 KiB
    u64* instr     = (u64*)(ws + o);    o += (size_t)BATCH * 256 * 64; // 128 KiB
    bool ok = (ws_size >= o);
    u64* calib_p = ok ? calib : (u64*)0;
    u64* instr_p = ok ? instr : (u64*)0;

    gather_k<<<(BATCH * NS + 255) / 256, 256, 0, stream>>>(S1, S2, idx, s1g, s2g,
                                                           cnt, calib_p);
    lists_k<<<2 * BATCH * NS / 4, 256, 0, stream>>>(s1g, s2g, rlist_g, clist_g);
    resolve_k<<<BATCH, 1024, 0, stream>>>(s1g, s2g, rlist_g, clist_g, loss_ws, cnt,
                                          (float*)d_out, instr_p);
}